// Round 1
// baseline (579.616 us; speedup 1.0000x reference)
//
#include <hip/hip_runtime.h>
#include <hip/hip_bf16.h>

// Problem constants
#define Bn   128
#define Tn   256
#define Cn   256
#define T1n  128
#define T2n  64
#define TTn  448   // Tn + T1n + T2n
#define EPSf 1e-5f

// ---------------- prep kernels ----------------

// wr[(k*C+ci)*C + co] = w[co*C*K + ci*K + k]
__global__ void prep_conv_w(const float* __restrict__ w, float* __restrict__ wr, int K) {
    int idx = blockIdx.x * blockDim.x + threadIdx.x;
    int total = Cn * Cn * K;
    if (idx >= total) return;
    int co = idx / (Cn * K);
    int r  = idx % (Cn * K);
    int ci = r / K;
    int k  = r % K;
    wr[(size_t)(k * Cn + ci) * Cn + co] = w[idx];
}

// wt[i*TT + j] = w[j*TT + i] * (j<=i)
__global__ void prep_triu(const float* __restrict__ w, float* __restrict__ wt) {
    int idx = blockIdx.x * blockDim.x + threadIdx.x;
    int total = TTn * TTn;
    if (idx >= total) return;
    int i = idx / TTn;
    int j = idx % TTn;
    wt[idx] = (j <= i) ? w[(size_t)j * TTn + i] : 0.0f;
}

// copy x [B,T,C] into cat rows [0..T) of [B,TT,C]
__global__ void copy_x(const float* __restrict__ x, float* __restrict__ cat) {
    size_t idx = (size_t)blockIdx.x * blockDim.x + threadIdx.x;  // in float4
    size_t tot = (size_t)Bn * Tn * Cn / 4;
    if (idx >= tot) return;
    size_t per_b = (size_t)Tn * Cn / 4;        // 16384
    size_t b  = idx / per_b;
    size_t r4 = idx % per_b;
    ((float4*)cat)[b * ((size_t)TTn * Cn / 4) + r4] = ((const float4*)x)[idx];
}

// ---------------- layernorm over a [nrows, C] slab per batch ----------------
__global__ __launch_bounds__(256) void ln_kernel(float* __restrict__ cat,
                                                 const float* __restrict__ g,
                                                 const float* __restrict__ beta,
                                                 int rowoff, int nelems) {
    float* p = cat + (size_t)blockIdx.x * (TTn * Cn) + (size_t)rowoff * Cn;
    int tid = threadIdx.x;
    float s = 0.f, ss = 0.f;
    for (int i = tid; i < nelems; i += 256) {
        float v = p[i];
        s += v;
        ss = fmaf(v, v, ss);
    }
    // wave64 reduce
    for (int o = 32; o > 0; o >>= 1) {
        s  += __shfl_down(s, o);
        ss += __shfl_down(ss, o);
    }
    __shared__ float sm[4], sm2[4];
    int wid = tid >> 6, lane = tid & 63;
    if (lane == 0) { sm[wid] = s; sm2[wid] = ss; }
    __syncthreads();
    if (tid == 0) {
        float S = 0.f, SS = 0.f;
        for (int w = 0; w < 4; ++w) { S += sm[w]; SS += sm2[w]; }
        float mu  = S / nelems;
        float var = SS / nelems - mu * mu;
        sm[0]  = mu;
        sm2[0] = rsqrtf(var + EPSf);
    }
    __syncthreads();
    float mu = sm[0], rs = sm2[0];
    for (int i = tid; i < nelems; i += 256) {
        p[i] = (p[i] - mu) * rs * g[i] + beta[i];
    }
}

// ---------------- tiled f32 GEMM ----------------
// C[m,n] = sum_k A[m,k] * B[k,n]  (+ epilogue)
// EPI 0: += bias[n]               (conv)
// EPI 1: += bias[m], hardswish    (triu layer 1)
// EPI 2: += bias[m]               (triu layer 2)
#define BM 64
#define BN 64
#define BK 16

template<int EPI>
__global__ __launch_bounds__(256) void gemm_k(const float* __restrict__ A, long astride, int lda,
                                              const float* __restrict__ Bm, long bstride, int ldb,
                                              const float* __restrict__ bias,
                                              float* __restrict__ Cm, long cstride, int ldc,
                                              int M, int N, int K) {
    int batch = blockIdx.z;
    const float* Ab = A + (size_t)batch * astride;
    const float* Bb = Bm + (size_t)batch * bstride;
    float* Cb = Cm + (size_t)batch * cstride;
    int m0 = blockIdx.y * BM, n0 = blockIdx.x * BN;

    __shared__ float As[BK][BM];   // k-major (transposed A tile)
    __shared__ float Bs[BK][BN];

    int tid = threadIdx.x;
    int tx = tid & 15, ty = tid >> 4;

    int ar = tid >> 2,  ac4 = (tid & 3) * 4;    // A tile: 64 rows x 4 float4
    int br = tid >> 4,  bc4 = (tid & 15) * 4;   // B tile: 16 rows x 16 float4

    float acc[4][4] = {};

    for (int k0 = 0; k0 < K; k0 += BK) {
        float4 av = *(const float4*)&Ab[(size_t)(m0 + ar) * lda + k0 + ac4];
        float4 bv = *(const float4*)&Bb[(size_t)(k0 + br) * ldb + n0 + bc4];
        __syncthreads();   // previous iteration's compute must finish
        As[ac4 + 0][ar] = av.x;
        As[ac4 + 1][ar] = av.y;
        As[ac4 + 2][ar] = av.z;
        As[ac4 + 3][ar] = av.w;
        *(float4*)&Bs[br][bc4] = bv;
        __syncthreads();
#pragma unroll
        for (int kk = 0; kk < BK; ++kk) {
            float4 a = *(const float4*)&As[kk][ty * 4];
            float4 b = *(const float4*)&Bs[kk][tx * 4];
            float aa[4] = {a.x, a.y, a.z, a.w};
            float bb[4] = {b.x, b.y, b.z, b.w};
#pragma unroll
            for (int r = 0; r < 4; ++r)
#pragma unroll
                for (int c = 0; c < 4; ++c)
                    acc[r][c] = fmaf(aa[r], bb[c], acc[r][c]);
        }
    }

#pragma unroll
    for (int r = 0; r < 4; ++r) {
        int m = m0 + ty * 4 + r;
        float4 v;
        float* vv = &v.x;
#pragma unroll
        for (int c = 0; c < 4; ++c) {
            float t = acc[r][c];
            if (EPI == 0) t += bias[n0 + tx * 4 + c];
            else          t += bias[m];
            if (EPI == 1) {
                float u = t + 3.0f;
                u = u < 0.f ? 0.f : (u > 6.f ? 6.f : u);
                t = t * u * (1.0f / 6.0f);
            }
            vv[c] = t;
        }
        *(float4*)&Cb[(size_t)m * ldc + n0 + tx * 4] = v;
    }
}

// ---------------- launch ----------------
extern "C" void kernel_launch(void* const* d_in, const int* in_sizes, int n_in,
                              void* d_out, int out_size, void* d_ws, size_t ws_size,
                              hipStream_t stream) {
    const float* x    = (const float*)d_in[0];
    const float* cw1  = (const float*)d_in[1];
    const float* cb1  = (const float*)d_in[2];
    const float* cw2  = (const float*)d_in[3];
    const float* cb2  = (const float*)d_in[4];
    const float* ln1g = (const float*)d_in[5];
    const float* ln1b = (const float*)d_in[6];
    const float* ln2g = (const float*)d_in[7];
    const float* ln2b = (const float*)d_in[8];
    const float* tw1  = (const float*)d_in[9];
    const float* tb1  = (const float*)d_in[10];
    const float* tw2  = (const float*)d_in[11];
    const float* tb2  = (const float*)d_in[12];
    float* out = (float*)d_out;

    float* ws  = (float*)d_ws;
    const size_t cat_sz = (size_t)Bn * TTn * Cn;        // 14,680,064
    float* cat = ws;
    float* z1  = cat + cat_sz;
    float* w1r = z1 + cat_sz;                           // 512*256
    float* w2r = w1r + 512 * 256;                       // 1024*256
    float* wm1 = w2r + 1024 * 256;                      // 448*448
    float* wm2 = wm1 + TTn * TTn;

    // --- prep ---
    prep_conv_w<<<(Cn * Cn * 2 + 255) / 256, 256, 0, stream>>>(cw1, w1r, 2);
    prep_conv_w<<<(Cn * Cn * 4 + 255) / 256, 256, 0, stream>>>(cw2, w2r, 4);
    prep_triu<<<(TTn * TTn + 255) / 256, 256, 0, stream>>>(tw1, wm1);
    prep_triu<<<(TTn * TTn + 255) / 256, 256, 0, stream>>>(tw2, wm2);

    // --- cat rows [0,256): x ---
    copy_x<<<(Bn * Tn * Cn / 4 + 255) / 256, 256, 0, stream>>>(x, cat);

    // --- conv1 -> cat rows [256,384) ---
    // A row m = x[b, 2m, :] (contiguous 512), lda=512; B = w1r [512x256]
    gemm_k<0><<<dim3(Cn / BN, T1n / BM, Bn), 256, 0, stream>>>(
        x, (long)Tn * Cn, 512,
        w1r, 0L, Cn,
        cb1,
        cat + (size_t)Tn * Cn, (long)TTn * Cn, Cn,
        T1n, Cn, 512);

    // --- conv2 -> cat rows [384,448) ---
    gemm_k<0><<<dim3(Cn / BN, T2n / BM, Bn), 256, 0, stream>>>(
        x, (long)Tn * Cn, 1024,
        w2r, 0L, Cn,
        cb2,
        cat + (size_t)(Tn + T1n) * Cn, (long)TTn * Cn, Cn,
        T2n, Cn, 1024);

    // --- layernorms in place ---
    ln_kernel<<<Bn, 256, 0, stream>>>(cat, ln1g, ln1b, Tn, T1n * Cn);
    ln_kernel<<<Bn, 256, 0, stream>>>(cat, ln2g, ln2b, Tn + T1n, T2n * Cn);

    // --- triu layer 1: z1 = hardswish(Wm1^T @ cat + b1) ---
    gemm_k<1><<<dim3(Cn / BN, TTn / BM, Bn), 256, 0, stream>>>(
        wm1, 0L, TTn,
        cat, (long)TTn * Cn, Cn,
        tb1,
        z1, (long)TTn * Cn, Cn,
        TTn, Cn, TTn);

    // --- triu layer 2: out = Wm2^T @ z1 + b2 ---
    gemm_k<2><<<dim3(Cn / BN, TTn / BM, Bn), 256, 0, stream>>>(
        wm2, 0L, TTn,
        z1, (long)TTn * Cn, Cn,
        tb2,
        out, (long)TTn * Cn, Cn,
        TTn, Cn, TTn);
}

// Round 2
// 216.237 us; speedup vs baseline: 2.6805x; 2.6805x over previous
//
#include <hip/hip_runtime.h>
#include <hip/hip_bf16.h>

#define Bn   128
#define Tn   256
#define Cn   256
#define T1n  128
#define T2n  64
#define TTn  448
#define EPSf 1e-5f

typedef __attribute__((ext_vector_type(8))) short short8;
typedef __attribute__((ext_vector_type(4))) short short4v;
typedef __attribute__((ext_vector_type(4))) float f32x4;

__device__ __forceinline__ unsigned short f2b(float f) {
    union { __hip_bfloat16 h; unsigned short u; } cv;
    cv.h = __float2bfloat16(f);   // RNE
    return cv.u;
}

__device__ __forceinline__ short8 cvt8(float4 a, float4 b) {
    short8 r;
    r[0] = (short)f2b(a.x); r[1] = (short)f2b(a.y); r[2] = (short)f2b(a.z); r[3] = (short)f2b(a.w);
    r[4] = (short)f2b(b.x); r[5] = (short)f2b(b.y); r[6] = (short)f2b(b.z); r[7] = (short)f2b(b.w);
    return r;
}

// ---------------- prep kernels (f32 -> bf16, layout reshapes) ----------------

// wt[co*(C*K) + k*C + ci] = bf16(w[co*(C*K) + ci*K + k])   (row co is k-contiguous index (k*C+ci))
__global__ void prep_conv_w(const float* __restrict__ wsrc, unsigned short* __restrict__ wt, int K) {
    int idx = blockIdx.x * blockDim.x + threadIdx.x;
    int CK = Cn * K;
    if (idx >= Cn * CK) return;
    int co = idx / CK, r = idx % CK;
    int k = r / Cn, ci = r % Cn;
    wt[idx] = f2b(wsrc[(size_t)co * CK + (size_t)ci * K + k]);
}

// wt[i*TT + j] = bf16(w[j*TT + i]) * (j<=i)   ([m][k] layout, k-contiguous)
__global__ void prep_triu(const float* __restrict__ wsrc, unsigned short* __restrict__ wt) {
    int idx = blockIdx.x * blockDim.x + threadIdx.x;
    if (idx >= TTn * TTn) return;
    int i = idx / TTn, j = idx % TTn;
    wt[idx] = (j <= i) ? f2b(wsrc[(size_t)j * TTn + i]) : (unsigned short)0;
}

// catb[b][c][t] = bf16(x[b][t][c]) for t in [0,256)  (tiled 64x64 transpose)
__global__ __launch_bounds__(256) void xpose_kernel(const float* __restrict__ x,
                                                    unsigned short* __restrict__ catb) {
    __shared__ float tl[64][65];
    int b = blockIdx.z, t0 = blockIdx.y * 64, c0 = blockIdx.x * 64;
    const float* xp = x + (size_t)b * Tn * Cn;
    int lr = threadIdx.x >> 4;
    int lc = (threadIdx.x & 15) * 4;
#pragma unroll
    for (int rr = 0; rr < 4; ++rr) {
        int row = lr + rr * 16;
        float4 v = *(const float4*)(xp + (size_t)(t0 + row) * Cn + c0 + lc);
        tl[lc + 0][row] = v.x; tl[lc + 1][row] = v.y;
        tl[lc + 2][row] = v.z; tl[lc + 3][row] = v.w;
    }
    __syncthreads();
    int cr = threadIdx.x >> 2, tq = (threadIdx.x & 3) * 16;
    unsigned short* qp = catb + (size_t)b * (TTn * Cn) + (size_t)(c0 + cr) * TTn + t0 + tq;
    short8 o0, o1;
#pragma unroll
    for (int j = 0; j < 8; ++j) {
        o0[j] = (short)f2b(tl[cr][tq + j]);
        o1[j] = (short)f2b(tl[cr][tq + 8 + j]);
    }
    *(short8*)(qp) = o0;
    *(short8*)(qp + 8) = o1;
}

// ---------------- joint layernorm over [C][Tc] slab per batch, emit bf16 into catb ----------------
template<int LG>
__global__ __launch_bounds__(256) void ln_kernel(const float* __restrict__ slab,
                                                 const float* __restrict__ g,
                                                 const float* __restrict__ be,
                                                 unsigned short* __restrict__ catb, int toff) {
    const int Tc = 1 << LG;
    const int n = Cn * Tc;
    const float* p = slab + (size_t)blockIdx.x * n;
    unsigned short* q = catb + (size_t)blockIdx.x * (TTn * Cn) + toff;
    int tid = threadIdx.x;
    float s = 0.f, ss = 0.f;
    for (int i = tid; i < n; i += 256) { float v = p[i]; s += v; ss = fmaf(v, v, ss); }
    for (int o = 32; o > 0; o >>= 1) { s += __shfl_down(s, o); ss += __shfl_down(ss, o); }
    __shared__ float sm[4], sm2[4];
    if ((tid & 63) == 0) { sm[tid >> 6] = s; sm2[tid >> 6] = ss; }
    __syncthreads();
    if (tid == 0) {
        float S = sm[0] + sm[1] + sm[2] + sm[3];
        float SS = sm2[0] + sm2[1] + sm2[2] + sm2[3];
        float mu = S / n;
        float var = SS / n - mu * mu;
        sm[0] = mu; sm2[0] = rsqrtf(var + EPSf);
    }
    __syncthreads();
    float mu = sm[0], rs = sm2[0];
    for (int i = tid; i < n; i += 256) {
        int c = i >> LG, t = i & (Tc - 1);
        float v = (p[i] - mu) * rs * g[(size_t)t * Cn + c] + be[(size_t)t * Cn + c];
        q[(size_t)c * TTn + t] = f2b(v);
    }
}

// ---------------- bf16 MFMA GEMM ----------------
// D[m][n] = sum_k A[m][k]*B[k][n], BM=64 BN=128 BK=64, 256 thr (4 waves 2x2).
// A source: f32 (AF32) or bf16, row-major [M][K] lda. B source: bf16 stored [n][k] (k-contig) ldb.
// LDS: As[m][k], Bs[n][k], both row=128B, XOR-swizzled byte^=((row&7)<<4).
// EPI 0: +bias[n], f32 store transposed (Cb[col*ldc + t], float4)       (conv)
// EPI 1: +bias[m], hardswish, bf16 store transposed (Cb[col*ldc + t])   (triu L1 -> z1b)
// EPI 2: +bias[m], f32 store normal (Cb[t*ldc + col])                   (triu L2 -> out)
// EPI 1/2 also exploit triangular A: k-tiles beyond m0+63 are zero -> skipped.
template<bool AF32, int EPI>
__global__ __launch_bounds__(256)
void gemm_mfma(const void* __restrict__ Av, long astride, int lda,
               const unsigned short* __restrict__ Bsrc, long bstride, int ldb,
               const float* __restrict__ bias,
               void* __restrict__ Cv, long cstride, int ldc,
               int K) {
    const int tid = threadIdx.x;
    const int lane = tid & 63;
    const int wid = tid >> 6;
    const int wr = wid >> 1, wc = wid & 1;
    const int bz = blockIdx.z;
    const int m0 = blockIdx.y * 64, n0 = blockIdx.x * 128;

    __shared__ unsigned short As[64 * 64];
    __shared__ unsigned short Bs[128 * 64];
    char* AsB = (char*)As;
    char* BsB = (char*)Bs;

    // staging indices
    const int ar = tid >> 2, akq = tid & 3;          // A: row, 16-elt k-quad
    const int bn_ = tid >> 1, bkh = (tid & 1) * 32;  // B: row, 32-elt k-half

    const float* Afp = (const float*)Av + (size_t)bz * astride + (size_t)(m0 + ar) * lda + akq * 16;
    const unsigned short* Ahp = (const unsigned short*)Av + (size_t)bz * astride + (size_t)(m0 + ar) * lda + akq * 16;
    const unsigned short* Bp = Bsrc + (size_t)bz * bstride + (size_t)(n0 + bn_) * ldb + bkh;

    const int awb = ar * 128 + akq * 32;
    const int aswz = (ar & 7) << 4;
    const int bwb = bn_ * 128 + bkh * 2;
    const int bswz = (bn_ & 7) << 4;

    short8 ra0, ra1, rb0, rb1, rb2, rb3;

    auto loadA = [&](int k0) {
        if constexpr (AF32) {
            const float* p = Afp + k0;
            float4 v0 = *(const float4*)(p);
            float4 v1 = *(const float4*)(p + 4);
            float4 v2 = *(const float4*)(p + 8);
            float4 v3 = *(const float4*)(p + 12);
            ra0 = cvt8(v0, v1);
            ra1 = cvt8(v2, v3);
        } else {
            ra0 = *(const short8*)(Ahp + k0);
            ra1 = *(const short8*)(Ahp + k0 + 8);
        }
    };
    auto loadB = [&](int k0) {
        rb0 = *(const short8*)(Bp + k0);
        rb1 = *(const short8*)(Bp + k0 + 8);
        rb2 = *(const short8*)(Bp + k0 + 16);
        rb3 = *(const short8*)(Bp + k0 + 24);
    };
    auto stage = [&]() {
        *(short8*)(AsB + ((awb) ^ aswz)) = ra0;
        *(short8*)(AsB + ((awb + 16) ^ aswz)) = ra1;
        *(short8*)(BsB + ((bwb) ^ bswz)) = rb0;
        *(short8*)(BsB + ((bwb + 16) ^ bswz)) = rb1;
        *(short8*)(BsB + ((bwb + 32) ^ bswz)) = rb2;
        *(short8*)(BsB + ((bwb + 48) ^ bswz)) = rb3;
    };

    // fragment read bases
    const int fl = lane & 15;
    const int fkb = (lane >> 4) * 16;            // k byte offset within a 32-elt k-step
    const int amb = (wr * 32 + fl) * 128;        // A row byte base
    const int bnb = (wc * 64 + fl) * 128;        // B row byte base
    const int fswz = (fl & 7) << 4;

    f32x4 acc[2][4];
#pragma unroll
    for (int i = 0; i < 2; ++i)
#pragma unroll
        for (int j = 0; j < 4; ++j) acc[i][j] = (f32x4){0.f, 0.f, 0.f, 0.f};

    // triangular skip: for TriU layers, A[m][k]==0 for k>m
    const int nkt = (EPI == 0) ? (K >> 6) : ((m0 >> 6) + 1);

    loadA(0);
    loadB(0);
    for (int kt = 0; kt < nkt; ++kt) {
        __syncthreads();
        stage();
        __syncthreads();
        if (kt + 1 < nkt) { loadA((kt + 1) * 64); loadB((kt + 1) * 64); }
#pragma unroll
        for (int ks = 0; ks < 2; ++ks) {
            const int kb = ks * 64 + fkb;
            short8 af0 = *(const short8*)(AsB + ((amb + kb) ^ fswz));
            short8 af1 = *(const short8*)(AsB + ((amb + 2048 + kb) ^ fswz));
            short8 bf0 = *(const short8*)(BsB + ((bnb + kb) ^ fswz));
            short8 bf1 = *(const short8*)(BsB + ((bnb + 2048 + kb) ^ fswz));
            short8 bf2 = *(const short8*)(BsB + ((bnb + 4096 + kb) ^ fswz));
            short8 bf3 = *(const short8*)(BsB + ((bnb + 6144 + kb) ^ fswz));
            acc[0][0] = __builtin_amdgcn_mfma_f32_16x16x32_bf16(af0, bf0, acc[0][0], 0, 0, 0);
            acc[0][1] = __builtin_amdgcn_mfma_f32_16x16x32_bf16(af0, bf1, acc[0][1], 0, 0, 0);
            acc[0][2] = __builtin_amdgcn_mfma_f32_16x16x32_bf16(af0, bf2, acc[0][2], 0, 0, 0);
            acc[0][3] = __builtin_amdgcn_mfma_f32_16x16x32_bf16(af0, bf3, acc[0][3], 0, 0, 0);
            acc[1][0] = __builtin_amdgcn_mfma_f32_16x16x32_bf16(af1, bf0, acc[1][0], 0, 0, 0);
            acc[1][1] = __builtin_amdgcn_mfma_f32_16x16x32_bf16(af1, bf1, acc[1][1], 0, 0, 0);
            acc[1][2] = __builtin_amdgcn_mfma_f32_16x16x32_bf16(af1, bf2, acc[1][2], 0, 0, 0);
            acc[1][3] = __builtin_amdgcn_mfma_f32_16x16x32_bf16(af1, bf3, acc[1][3], 0, 0, 0);
        }
    }

    // epilogue: D fragment mapping col = lane&15, row = (lane>>4)*4 + reg  [m89/m91]
    const int lrow = (lane >> 4) * 4;
#pragma unroll
    for (int mf = 0; mf < 2; ++mf) {
        const int trow = m0 + wr * 32 + mf * 16 + lrow;
#pragma unroll
        for (int nf = 0; nf < 4; ++nf) {
            const int col = n0 + wc * 64 + nf * 16 + fl;
            f32x4 v = acc[mf][nf];
            if (EPI == 0) {
                v += bias[col];
                float* Cb = (float*)Cv + (size_t)bz * cstride + (size_t)col * ldc + trow;
                *(f32x4*)Cb = v;
            } else if (EPI == 1) {
                f32x4 bv = *(const f32x4*)(bias + trow);
                v += bv;
                unsigned short* Cb = (unsigned short*)Cv + (size_t)bz * cstride + (size_t)col * ldc + trow;
                short4v pk;
#pragma unroll
                for (int r = 0; r < 4; ++r) {
                    float t = v[r];
                    float u = fminf(fmaxf(t + 3.f, 0.f), 6.f);
                    t = t * u * (1.f / 6.f);
                    pk[r] = (short)f2b(t);
                }
                *(short4v*)Cb = pk;
            } else {
                f32x4 bv = *(const f32x4*)(bias + trow);
                v += bv;
                float* Cb = (float*)Cv + (size_t)bz * cstride + (size_t)trow * ldc + col;
#pragma unroll
                for (int r = 0; r < 4; ++r) Cb[(size_t)r * ldc] = v[r];
            }
        }
    }
}

// ---------------- launch ----------------
extern "C" void kernel_launch(void* const* d_in, const int* in_sizes, int n_in,
                              void* d_out, int out_size, void* d_ws, size_t ws_size,
                              hipStream_t stream) {
    const float* x    = (const float*)d_in[0];
    const float* cw1  = (const float*)d_in[1];
    const float* cb1  = (const float*)d_in[2];
    const float* cw2  = (const float*)d_in[3];
    const float* cb2  = (const float*)d_in[4];
    const float* ln1g = (const float*)d_in[5];
    const float* ln1b = (const float*)d_in[6];
    const float* ln2g = (const float*)d_in[7];
    const float* ln2b = (const float*)d_in[8];
    const float* tw1  = (const float*)d_in[9];
    const float* tb1  = (const float*)d_in[10];
    const float* tw2  = (const float*)d_in[11];
    const float* tb2  = (const float*)d_in[12];
    float* out = (float*)d_out;

    char* w = (char*)d_ws;
    unsigned short* catb = (unsigned short*)w;                  // bf16 [B][C][TT]   29,360,128 B
    unsigned short* z1b  = (unsigned short*)(w + 29360128);     // bf16 [B][C][TT]   29,360,128 B
    float*          c1t  = (float*)(w + 58720256);              // f32 [B][C][T1]    16,777,216 B
    float*          c2t  = (float*)(w + 75497472);              // f32 [B][C][T2]     8,388,608 B
    unsigned short* w1rT = (unsigned short*)(w + 83886080);     // bf16 [C][512]
    unsigned short* w2rT = (unsigned short*)(w + 84148224);     // bf16 [C][1024]
    unsigned short* wm1b = (unsigned short*)(w + 84672512);     // bf16 [TT][TT]
    unsigned short* wm2b = (unsigned short*)(w + 85073920);     // bf16 [TT][TT]

    prep_conv_w<<<(Cn * Cn * 2 + 255) / 256, 256, 0, stream>>>(cw1, w1rT, 2);
    prep_conv_w<<<(Cn * Cn * 4 + 255) / 256, 256, 0, stream>>>(cw2, w2rT, 4);
    prep_triu<<<(TTn * TTn + 255) / 256, 256, 0, stream>>>(tw1, wm1b);
    prep_triu<<<(TTn * TTn + 255) / 256, 256, 0, stream>>>(tw2, wm2b);

    // x -> catb rows (channel-major, t in [0,256))
    xpose_kernel<<<dim3(4, 4, Bn), 256, 0, stream>>>(x, catb);

    // conv1: A = x (f32, lda=512), B = w1rT, D -> c1t[b][co][t1] (transposed f32)
    gemm_mfma<true, 0><<<dim3(2, 2, Bn), 256, 0, stream>>>(
        x, 65536L, 512, w1rT, 0L, 512, cb1, c1t, (long)Cn * T1n, T1n, 512);
    // conv2: A = x (f32, lda=1024), B = w2rT, D -> c2t
    gemm_mfma<true, 0><<<dim3(2, 1, Bn), 256, 0, stream>>>(
        x, 65536L, 1024, w2rT, 0L, 1024, cb2, c2t, (long)Cn * T2n, T2n, 1024);

    // layernorms: slab stats + affine, emit bf16 into catb rows [256,384) and [384,448)
    ln_kernel<7><<<Bn, 256, 0, stream>>>(c1t, ln1g, ln1b, catb, Tn);
    ln_kernel<6><<<Bn, 256, 0, stream>>>(c2t, ln2g, ln2b, catb, Tn + T1n);

    // TriU layer 1: A = wm1b [m][k], B = catb [n][k], D -> z1b bf16 (hardswish)
    gemm_mfma<false, 1><<<dim3(2, 7, Bn), 256, 0, stream>>>(
        wm1b, 0L, TTn, catb, (long)TTn * Cn, TTn, tb1, z1b, (long)TTn * Cn, TTn, TTn);

    // TriU layer 2: A = wm2b, B = z1b, D -> out f32 [b][t][c]
    gemm_mfma<false, 2><<<dim3(2, 7, Bn), 256, 0, stream>>>(
        wm2b, 0L, TTn, z1b, (long)TTn * Cn, TTn, tb2, out, (long)TTn * Cn, Cn, TTn);
}

// Round 3
// 137.988 us; speedup vs baseline: 4.2005x; 1.5671x over previous
//
#include <hip/hip_runtime.h>
#include <hip/hip_bf16.h>

#define Bn   128
#define Tn   256
#define Cn   256
#define T1n  128
#define T2n  64
#define TTn  448
#define EPSf 1e-5f
#define NSl  8

typedef __attribute__((ext_vector_type(8))) short short8;
typedef __attribute__((ext_vector_type(4))) short short4v;
typedef __attribute__((ext_vector_type(4))) float f32x4;

__device__ __forceinline__ unsigned short f2b(float f) {
    union { __hip_bfloat16 h; unsigned short u; } cv;
    cv.h = __float2bfloat16(f);   // RNE
    return cv.u;
}

__device__ __forceinline__ short8 cvt8(float4 a, float4 b) {
    short8 r;
    r[0] = (short)f2b(a.x); r[1] = (short)f2b(a.y); r[2] = (short)f2b(a.z); r[3] = (short)f2b(a.w);
    r[4] = (short)f2b(b.x); r[5] = (short)f2b(b.y); r[6] = (short)f2b(b.z); r[7] = (short)f2b(b.w);
    return r;
}

// ---------------- prep kernels ----------------

// wt[co*(C*K) + k*C + ci] = bf16(w[co*(C*K) + ci*K + k])
__global__ void prep_conv_w(const float* __restrict__ wsrc, unsigned short* __restrict__ wt, int K) {
    int idx = blockIdx.x * blockDim.x + threadIdx.x;
    int CK = Cn * K;
    if (idx >= Cn * CK) return;
    int co = idx / CK, r = idx % CK;
    int k = r / Cn, ci = r % Cn;
    wt[idx] = f2b(wsrc[(size_t)co * CK + (size_t)ci * K + k]);
}

// wt[i*TT + j] = bf16(w[j*TT + i]) * (j<=i)
__global__ void prep_triu(const float* __restrict__ wsrc, unsigned short* __restrict__ wt) {
    int idx = blockIdx.x * blockDim.x + threadIdx.x;
    if (idx >= TTn * TTn) return;
    int i = idx / TTn, j = idx % TTn;
    wt[idx] = (j <= i) ? f2b(wsrc[(size_t)j * TTn + i]) : (unsigned short)0;
}

// dst[c*R + r] = src[r*C + c]  (transpose LN affine params to [c][t])
__global__ void xpose_f32(const float* __restrict__ src, float* __restrict__ dst, int R) {
    int idx = blockIdx.x * blockDim.x + threadIdx.x;
    if (idx >= R * Cn) return;
    int c = idx / R, r = idx % R;
    dst[idx] = src[(size_t)r * Cn + c];
}

// catb[b][c][t] = bf16(x[b][t][c]) for t in [0,256)
__global__ __launch_bounds__(256) void xpose_kernel(const float* __restrict__ x,
                                                    unsigned short* __restrict__ catb) {
    __shared__ float tl[64][65];
    int b = blockIdx.z, t0 = blockIdx.y * 64, c0 = blockIdx.x * 64;
    const float* xp = x + (size_t)b * Tn * Cn;
    int lr = threadIdx.x >> 4;
    int lc = (threadIdx.x & 15) * 4;
#pragma unroll
    for (int rr = 0; rr < 4; ++rr) {
        int row = lr + rr * 16;
        float4 v = *(const float4*)(xp + (size_t)(t0 + row) * Cn + c0 + lc);
        tl[lc + 0][row] = v.x; tl[lc + 1][row] = v.y;
        tl[lc + 2][row] = v.z; tl[lc + 3][row] = v.w;
    }
    __syncthreads();
    int cr = threadIdx.x >> 2, tq = (threadIdx.x & 3) * 16;
    unsigned short* qp = catb + (size_t)b * (TTn * Cn) + (size_t)(c0 + cr) * TTn + t0 + tq;
    short8 o0, o1;
#pragma unroll
    for (int j = 0; j < 8; ++j) {
        o0[j] = (short)f2b(tl[cr][tq + j]);
        o1[j] = (short)f2b(tl[cr][tq + 8 + j]);
    }
    *(short8*)(qp) = o0;
    *(short8*)(qp + 8) = o1;
}

// ---------------- layernorm: reduce + apply ----------------
// slab: f32 [B][C][Tc]; partial sums ps[(b*NS+s)*2 + {0,1}]
template<int LG>
__global__ __launch_bounds__(256) void ln_reduce(const float* __restrict__ slab,
                                                 float* __restrict__ ps) {
    const int n = Cn << LG;
    const int chunk = n / NSl;
    const float* p = slab + (size_t)blockIdx.y * n + (size_t)blockIdx.x * chunk;
    float s = 0.f, ss = 0.f;
    for (int i = threadIdx.x * 4; i < chunk; i += 256 * 4) {
        float4 v = *(const float4*)(p + i);
        s += v.x + v.y + v.z + v.w;
        ss = fmaf(v.x, v.x, ss); ss = fmaf(v.y, v.y, ss);
        ss = fmaf(v.z, v.z, ss); ss = fmaf(v.w, v.w, ss);
    }
    for (int o = 32; o > 0; o >>= 1) { s += __shfl_down(s, o); ss += __shfl_down(ss, o); }
    __shared__ float sm[4], sm2[4];
    int tid = threadIdx.x;
    if ((tid & 63) == 0) { sm[tid >> 6] = s; sm2[tid >> 6] = ss; }
    __syncthreads();
    if (tid == 0) {
        float S = sm[0] + sm[1] + sm[2] + sm[3];
        float SS = sm2[0] + sm2[1] + sm2[2] + sm2[3];
        ps[((size_t)blockIdx.y * NSl + blockIdx.x) * 2 + 0] = S;
        ps[((size_t)blockIdx.y * NSl + blockIdx.x) * 2 + 1] = SS;
    }
}

// normalize + affine, emit bf16 into catb (channel-major). gt/bt are [c][t].
template<int LG>
__global__ __launch_bounds__(256) void ln_apply(const float* __restrict__ slab,
                                                const float* __restrict__ gt,
                                                const float* __restrict__ bt,
                                                const float* __restrict__ ps,
                                                unsigned short* __restrict__ catb, int toff) {
    const int n = Cn << LG;
    const int Tc = 1 << LG;
    const int b = blockIdx.y;
    float S = 0.f, SS = 0.f;
#pragma unroll
    for (int s_ = 0; s_ < NSl; ++s_) {
        S  += ps[((size_t)b * NSl + s_) * 2 + 0];
        SS += ps[((size_t)b * NSl + s_) * 2 + 1];
    }
    float mu = S / n;
    float rs = rsqrtf(SS / n - mu * mu + EPSf);

    const int per = n / gridDim.x;
    const int base = blockIdx.x * per;
    const float* p = slab + (size_t)b * n;
    unsigned short* q = catb + (size_t)b * (TTn * Cn) + toff;
    for (int i = base + threadIdx.x * 8; i < base + per; i += 256 * 8) {
        int c = i >> LG, t = i & (Tc - 1);
        float4 v0 = *(const float4*)(p + i);
        float4 v1 = *(const float4*)(p + i + 4);
        float4 g0 = *(const float4*)(gt + i);
        float4 g1 = *(const float4*)(gt + i + 4);
        float4 b0 = *(const float4*)(bt + i);
        float4 b1 = *(const float4*)(bt + i + 4);
        float4 o0, o1;
        o0.x = fmaf((v0.x - mu) * rs, g0.x, b0.x);
        o0.y = fmaf((v0.y - mu) * rs, g0.y, b0.y);
        o0.z = fmaf((v0.z - mu) * rs, g0.z, b0.z);
        o0.w = fmaf((v0.w - mu) * rs, g0.w, b0.w);
        o1.x = fmaf((v1.x - mu) * rs, g1.x, b1.x);
        o1.y = fmaf((v1.y - mu) * rs, g1.y, b1.y);
        o1.z = fmaf((v1.z - mu) * rs, g1.z, b1.z);
        o1.w = fmaf((v1.w - mu) * rs, g1.w, b1.w);
        *(short8*)(q + (size_t)c * TTn + t) = cvt8(o0, o1);
    }
}

// ---------------- bf16 MFMA GEMM (unchanged from round 2) ----------------
template<bool AF32, int EPI>
__global__ __launch_bounds__(256)
void gemm_mfma(const void* __restrict__ Av, long astride, int lda,
               const unsigned short* __restrict__ Bsrc, long bstride, int ldb,
               const float* __restrict__ bias,
               void* __restrict__ Cv, long cstride, int ldc,
               int K) {
    const int tid = threadIdx.x;
    const int lane = tid & 63;
    const int wid = tid >> 6;
    const int wr = wid >> 1, wc = wid & 1;
    const int bz = blockIdx.z;
    const int m0 = blockIdx.y * 64, n0 = blockIdx.x * 128;

    __shared__ unsigned short As[64 * 64];
    __shared__ unsigned short Bs[128 * 64];
    char* AsB = (char*)As;
    char* BsB = (char*)Bs;

    const int ar = tid >> 2, akq = tid & 3;
    const int bn_ = tid >> 1, bkh = (tid & 1) * 32;

    const float* Afp = (const float*)Av + (size_t)bz * astride + (size_t)(m0 + ar) * lda + akq * 16;
    const unsigned short* Ahp = (const unsigned short*)Av + (size_t)bz * astride + (size_t)(m0 + ar) * lda + akq * 16;
    const unsigned short* Bp = Bsrc + (size_t)bz * bstride + (size_t)(n0 + bn_) * ldb + bkh;

    const int awb = ar * 128 + akq * 32;
    const int aswz = (ar & 7) << 4;
    const int bwb = bn_ * 128 + bkh * 2;
    const int bswz = (bn_ & 7) << 4;

    short8 ra0, ra1, rb0, rb1, rb2, rb3;

    auto loadA = [&](int k0) {
        if constexpr (AF32) {
            const float* p = Afp + k0;
            float4 v0 = *(const float4*)(p);
            float4 v1 = *(const float4*)(p + 4);
            float4 v2 = *(const float4*)(p + 8);
            float4 v3 = *(const float4*)(p + 12);
            ra0 = cvt8(v0, v1);
            ra1 = cvt8(v2, v3);
        } else {
            ra0 = *(const short8*)(Ahp + k0);
            ra1 = *(const short8*)(Ahp + k0 + 8);
        }
    };
    auto loadB = [&](int k0) {
        rb0 = *(const short8*)(Bp + k0);
        rb1 = *(const short8*)(Bp + k0 + 8);
        rb2 = *(const short8*)(Bp + k0 + 16);
        rb3 = *(const short8*)(Bp + k0 + 24);
    };
    auto stage = [&]() {
        *(short8*)(AsB + ((awb) ^ aswz)) = ra0;
        *(short8*)(AsB + ((awb + 16) ^ aswz)) = ra1;
        *(short8*)(BsB + ((bwb) ^ bswz)) = rb0;
        *(short8*)(BsB + ((bwb + 16) ^ bswz)) = rb1;
        *(short8*)(BsB + ((bwb + 32) ^ bswz)) = rb2;
        *(short8*)(BsB + ((bwb + 48) ^ bswz)) = rb3;
    };

    const int fl = lane & 15;
    const int fkb = (lane >> 4) * 16;
    const int amb = (wr * 32 + fl) * 128;
    const int bnb = (wc * 64 + fl) * 128;
    const int fswz = (fl & 7) << 4;

    f32x4 acc[2][4];
#pragma unroll
    for (int i = 0; i < 2; ++i)
#pragma unroll
        for (int j = 0; j < 4; ++j) acc[i][j] = (f32x4){0.f, 0.f, 0.f, 0.f};

    const int nkt = (EPI == 0) ? (K >> 6) : ((m0 >> 6) + 1);

    loadA(0);
    loadB(0);
    for (int kt = 0; kt < nkt; ++kt) {
        __syncthreads();
        stage();
        __syncthreads();
        if (kt + 1 < nkt) { loadA((kt + 1) * 64); loadB((kt + 1) * 64); }
#pragma unroll
        for (int ks = 0; ks < 2; ++ks) {
            const int kb = ks * 64 + fkb;
            short8 af0 = *(const short8*)(AsB + ((amb + kb) ^ fswz));
            short8 af1 = *(const short8*)(AsB + ((amb + 2048 + kb) ^ fswz));
            short8 bf0 = *(const short8*)(BsB + ((bnb + kb) ^ fswz));
            short8 bf1 = *(const short8*)(BsB + ((bnb + 2048 + kb) ^ fswz));
            short8 bf2 = *(const short8*)(BsB + ((bnb + 4096 + kb) ^ fswz));
            short8 bf3 = *(const short8*)(BsB + ((bnb + 6144 + kb) ^ fswz));
            acc[0][0] = __builtin_amdgcn_mfma_f32_16x16x32_bf16(af0, bf0, acc[0][0], 0, 0, 0);
            acc[0][1] = __builtin_amdgcn_mfma_f32_16x16x32_bf16(af0, bf1, acc[0][1], 0, 0, 0);
            acc[0][2] = __builtin_amdgcn_mfma_f32_16x16x32_bf16(af0, bf2, acc[0][2], 0, 0, 0);
            acc[0][3] = __builtin_amdgcn_mfma_f32_16x16x32_bf16(af0, bf3, acc[0][3], 0, 0, 0);
            acc[1][0] = __builtin_amdgcn_mfma_f32_16x16x32_bf16(af1, bf0, acc[1][0], 0, 0, 0);
            acc[1][1] = __builtin_amdgcn_mfma_f32_16x16x32_bf16(af1, bf1, acc[1][1], 0, 0, 0);
            acc[1][2] = __builtin_amdgcn_mfma_f32_16x16x32_bf16(af1, bf2, acc[1][2], 0, 0, 0);
            acc[1][3] = __builtin_amdgcn_mfma_f32_16x16x32_bf16(af1, bf3, acc[1][3], 0, 0, 0);
        }
    }

    const int lrow = (lane >> 4) * 4;
#pragma unroll
    for (int mf = 0; mf < 2; ++mf) {
        const int trow = m0 + wr * 32 + mf * 16 + lrow;
#pragma unroll
        for (int nf = 0; nf < 4; ++nf) {
            const int col = n0 + wc * 64 + nf * 16 + fl;
            f32x4 v = acc[mf][nf];
            if (EPI == 0) {
                v += bias[col];
                float* Cb = (float*)Cv + (size_t)bz * cstride + (size_t)col * ldc + trow;
                *(f32x4*)Cb = v;
            } else if (EPI == 1) {
                f32x4 bv = *(const f32x4*)(bias + trow);
                v += bv;
                unsigned short* Cb = (unsigned short*)Cv + (size_t)bz * cstride + (size_t)col * ldc + trow;
                short4v pk;
#pragma unroll
                for (int r = 0; r < 4; ++r) {
                    float t = v[r];
                    float u = fminf(fmaxf(t + 3.f, 0.f), 6.f);
                    t = t * u * (1.f / 6.f);
                    pk[r] = (short)f2b(t);
                }
                *(short4v*)Cb = pk;
            } else {
                f32x4 bv = *(const f32x4*)(bias + trow);
                v += bv;
                float* Cb = (float*)Cv + (size_t)bz * cstride + (size_t)trow * ldc + col;
#pragma unroll
                for (int r = 0; r < 4; ++r) Cb[(size_t)r * ldc] = v[r];
            }
        }
    }
}

// ---------------- launch ----------------
extern "C" void kernel_launch(void* const* d_in, const int* in_sizes, int n_in,
                              void* d_out, int out_size, void* d_ws, size_t ws_size,
                              hipStream_t stream) {
    const float* x    = (const float*)d_in[0];
    const float* cw1  = (const float*)d_in[1];
    const float* cb1  = (const float*)d_in[2];
    const float* cw2  = (const float*)d_in[3];
    const float* cb2  = (const float*)d_in[4];
    const float* ln1g = (const float*)d_in[5];
    const float* ln1b = (const float*)d_in[6];
    const float* ln2g = (const float*)d_in[7];
    const float* ln2b = (const float*)d_in[8];
    const float* tw1  = (const float*)d_in[9];
    const float* tb1  = (const float*)d_in[10];
    const float* tw2  = (const float*)d_in[11];
    const float* tb2  = (const float*)d_in[12];
    float* out = (float*)d_out;

    char* w = (char*)d_ws;
    unsigned short* catb = (unsigned short*)w;                  // bf16 [B][C][TT]
    unsigned short* z1b  = (unsigned short*)(w + 29360128);     // bf16 [B][C][TT]
    float*          c1t  = (float*)(w + 58720256);              // f32 [B][C][T1]
    float*          c2t  = (float*)(w + 75497472);              // f32 [B][C][T2]
    unsigned short* w1rT = (unsigned short*)(w + 83886080);
    unsigned short* w2rT = (unsigned short*)(w + 84148224);
    unsigned short* wm1b = (unsigned short*)(w + 84672512);
    unsigned short* wm2b = (unsigned short*)(w + 85073920);
    float*          gt1  = (float*)(w + 85475328);              // f32 [C][T1]
    float*          bt1  = (float*)(w + 85606400);
    float*          gt2  = (float*)(w + 85737472);              // f32 [C][T2]
    float*          bt2  = (float*)(w + 85803008);
    float*          ps1  = (float*)(w + 85868544);              // [B][NS][2]
    float*          ps2  = (float*)(w + 85876736);

    prep_conv_w<<<(Cn * Cn * 2 + 255) / 256, 256, 0, stream>>>(cw1, w1rT, 2);
    prep_conv_w<<<(Cn * Cn * 4 + 255) / 256, 256, 0, stream>>>(cw2, w2rT, 4);
    prep_triu<<<(TTn * TTn + 255) / 256, 256, 0, stream>>>(tw1, wm1b);
    prep_triu<<<(TTn * TTn + 255) / 256, 256, 0, stream>>>(tw2, wm2b);
    xpose_f32<<<(T1n * Cn + 255) / 256, 256, 0, stream>>>(ln1g, gt1, T1n);
    xpose_f32<<<(T1n * Cn + 255) / 256, 256, 0, stream>>>(ln1b, bt1, T1n);
    xpose_f32<<<(T2n * Cn + 255) / 256, 256, 0, stream>>>(ln2g, gt2, T2n);
    xpose_f32<<<(T2n * Cn + 255) / 256, 256, 0, stream>>>(ln2b, bt2, T2n);

    // x -> catb (channel-major, t in [0,256))
    xpose_kernel<<<dim3(4, 4, Bn), 256, 0, stream>>>(x, catb);

    // conv1 / conv2 -> transposed f32 slabs
    gemm_mfma<true, 0><<<dim3(2, 2, Bn), 256, 0, stream>>>(
        x, 65536L, 512, w1rT, 0L, 512, cb1, c1t, (long)Cn * T1n, T1n, 512);
    gemm_mfma<true, 0><<<dim3(2, 1, Bn), 256, 0, stream>>>(
        x, 65536L, 1024, w2rT, 0L, 1024, cb2, c2t, (long)Cn * T2n, T2n, 1024);

    // layernorms
    ln_reduce<7><<<dim3(NSl, Bn), 256, 0, stream>>>(c1t, ps1);
    ln_reduce<6><<<dim3(NSl, Bn), 256, 0, stream>>>(c2t, ps2);
    ln_apply<7><<<dim3(16, Bn), 256, 0, stream>>>(c1t, gt1, bt1, ps1, catb, Tn);
    ln_apply<6><<<dim3(8, Bn), 256, 0, stream>>>(c2t, gt2, bt2, ps2, catb, Tn + T1n);

    // TriU layer 1 -> z1b (bf16, hardswish)
    gemm_mfma<false, 1><<<dim3(2, 7, Bn), 256, 0, stream>>>(
        wm1b, 0L, TTn, catb, (long)TTn * Cn, TTn, tb1, z1b, (long)TTn * Cn, TTn, TTn);

    // TriU layer 2 -> out (f32 [b][t][c])
    gemm_mfma<false, 2><<<dim3(2, 7, Bn), 256, 0, stream>>>(
        wm2b, 0L, TTn, z1b, (long)TTn * Cn, TTn, tb2, out, (long)TTn * Cn, Cn, TTn);
}

// Round 4
// 113.562 us; speedup vs baseline: 5.1039x; 1.2151x over previous
//
#include <hip/hip_runtime.h>
#include <hip/hip_bf16.h>

#define Bn   128
#define Tn   256
#define Cn   256
#define T1n  128
#define T2n  64
#define TTn  448
#define EPSf 1e-5f

typedef __attribute__((ext_vector_type(8))) short short8;
typedef __attribute__((ext_vector_type(4))) short short4v;
typedef __attribute__((ext_vector_type(4))) float f32x4;

__device__ __forceinline__ unsigned short f2b(float f) {
    union { __hip_bfloat16 h; unsigned short u; } cv;
    cv.h = __float2bfloat16(f);   // RNE
    return cv.u;
}

__device__ __forceinline__ short8 cvt8(float4 a, float4 b) {
    short8 r;
    r[0] = (short)f2b(a.x); r[1] = (short)f2b(a.y); r[2] = (short)f2b(a.z); r[3] = (short)f2b(a.w);
    r[4] = (short)f2b(b.x); r[5] = (short)f2b(b.y); r[6] = (short)f2b(b.z); r[7] = (short)f2b(b.w);
    return r;
}

// ---------------- one merged prep kernel ----------------
// Flat index space over 8 small reshape/convert tasks:
//  [0,131072)        w1rT[co*512 + k*256+ci]  = bf16(cw1[co*512 + ci*2 + k])
//  [..,+262144)      w2rT[co*1024+ k*256+ci]  = bf16(cw2[co*1024+ ci*4 + k])
//  [..,+200704)      wm1b[i*448+j] = (j<=i) ? bf16(tw1[j*448+i]) : 0
//  [..,+200704)      wm2b  likewise
//  [..,+32768)       gt1[c*128+r] = ln1g[r*256+c]
//  [..,+32768)       bt1          = ln1b
//  [..,+16384)       gt2[c*64+r]  = ln2g[r*256+c]
//  [..,+16384)       bt2          = ln2b
__global__ __launch_bounds__(256) void prep_all(
        const float* __restrict__ cw1, const float* __restrict__ cw2,
        const float* __restrict__ tw1, const float* __restrict__ tw2,
        const float* __restrict__ ln1g, const float* __restrict__ ln1b,
        const float* __restrict__ ln2g, const float* __restrict__ ln2b,
        unsigned short* __restrict__ w1rT, unsigned short* __restrict__ w2rT,
        unsigned short* __restrict__ wm1b, unsigned short* __restrict__ wm2b,
        float* __restrict__ gt1, float* __restrict__ bt1,
        float* __restrict__ gt2, float* __restrict__ bt2) {
    int idx = blockIdx.x * 256 + threadIdx.x;
    if (idx < 131072) {
        int co = idx >> 9, r = idx & 511, k = r >> 8, ci = r & 255;
        w1rT[idx] = f2b(cw1[(size_t)co * 512 + ci * 2 + k]);
    } else if ((idx -= 131072) < 262144) {
        int co = idx >> 10, r = idx & 1023, k = r >> 8, ci = r & 255;
        w2rT[idx] = f2b(cw2[(size_t)co * 1024 + ci * 4 + k]);
    } else if ((idx -= 262144) < 200704) {
        int i = idx / TTn, j = idx % TTn;
        wm1b[idx] = (j <= i) ? f2b(tw1[(size_t)j * TTn + i]) : (unsigned short)0;
    } else if ((idx -= 200704) < 200704) {
        int i = idx / TTn, j = idx % TTn;
        wm2b[idx] = (j <= i) ? f2b(tw2[(size_t)j * TTn + i]) : (unsigned short)0;
    } else if ((idx -= 200704) < 32768) {
        int c = idx >> 7, r = idx & 127;
        gt1[idx] = ln1g[(size_t)r * Cn + c];
    } else if ((idx -= 32768) < 32768) {
        int c = idx >> 7, r = idx & 127;
        bt1[idx] = ln1b[(size_t)r * Cn + c];
    } else if ((idx -= 32768) < 16384) {
        int c = idx >> 6, r = idx & 63;
        gt2[idx] = ln2g[(size_t)r * Cn + c];
    } else if ((idx -= 16384) < 16384) {
        int c = idx >> 6, r = idx & 63;
        bt2[idx] = ln2b[(size_t)r * Cn + c];
    }
}

// catb[b][c][t] = bf16(x[b][t][c]) for t in [0,256)
__global__ __launch_bounds__(256) void xpose_kernel(const float* __restrict__ x,
                                                    unsigned short* __restrict__ catb) {
    __shared__ float tl[64][65];
    int b = blockIdx.z, t0 = blockIdx.y * 64, c0 = blockIdx.x * 64;
    const float* xp = x + (size_t)b * Tn * Cn;
    int lr = threadIdx.x >> 4;
    int lc = (threadIdx.x & 15) * 4;
#pragma unroll
    for (int rr = 0; rr < 4; ++rr) {
        int row = lr + rr * 16;
        float4 v = *(const float4*)(xp + (size_t)(t0 + row) * Cn + c0 + lc);
        tl[lc + 0][row] = v.x; tl[lc + 1][row] = v.y;
        tl[lc + 2][row] = v.z; tl[lc + 3][row] = v.w;
    }
    __syncthreads();
    int cr = threadIdx.x >> 2, tq = (threadIdx.x & 3) * 16;
    unsigned short* qp = catb + (size_t)b * (TTn * Cn) + (size_t)(c0 + cr) * TTn + t0 + tq;
    short8 o0, o1;
#pragma unroll
    for (int j = 0; j < 8; ++j) {
        o0[j] = (short)f2b(tl[cr][tq + j]);
        o1[j] = (short)f2b(tl[cr][tq + 8 + j]);
    }
    *(short8*)(qp) = o0;
    *(short8*)(qp + 8) = o1;
}

// ---------------- merged layernorm apply (both scales) ----------------
// blockIdx.x < 16 : slab1 ([C][128] per b), chunks of 2048 elems
// blockIdx.x >= 16: slab2 ([C][64]  per b), chunks of 2048 elems
__global__ __launch_bounds__(256) void ln_apply_both(
        const float* __restrict__ c1t, const float* __restrict__ c2t,
        const float* __restrict__ gt1, const float* __restrict__ bt1,
        const float* __restrict__ gt2, const float* __restrict__ bt2,
        const float* __restrict__ ps1, const float* __restrict__ ps2,
        unsigned short* __restrict__ catb) {
    const int b = blockIdx.y, bx = blockIdx.x;
    const float *p, *g, *be;
    unsigned short* q;
    int LG, n, base;
    float S = 0.f, SS = 0.f;
    if (bx < 16) {
        n = Cn * T1n; LG = 7;
        p = c1t + (size_t)b * n; g = gt1; be = bt1;
        q = catb + (size_t)b * (TTn * Cn) + Tn;
#pragma unroll
        for (int s_ = 0; s_ < 4; ++s_) { S += ps1[b * 8 + s_ * 2]; SS += ps1[b * 8 + s_ * 2 + 1]; }
        base = bx * 2048;
    } else {
        n = Cn * T2n; LG = 6;
        p = c2t + (size_t)b * n; g = gt2; be = bt2;
        q = catb + (size_t)b * (TTn * Cn) + Tn + T1n;
#pragma unroll
        for (int s_ = 0; s_ < 2; ++s_) { S += ps2[b * 4 + s_ * 2]; SS += ps2[b * 4 + s_ * 2 + 1]; }
        base = (bx - 16) * 2048;
    }
    float mu = S / n;
    float rs = rsqrtf(SS / n - mu * mu + EPSf);

    int i = base + threadIdx.x * 8;
    int c = i >> LG, t = i & ((1 << LG) - 1);
    float4 v0 = *(const float4*)(p + i);
    float4 v1 = *(const float4*)(p + i + 4);
    float4 g0 = *(const float4*)(g + i);
    float4 g1 = *(const float4*)(g + i + 4);
    float4 b0 = *(const float4*)(be + i);
    float4 b1 = *(const float4*)(be + i + 4);
    float4 o0, o1;
    o0.x = fmaf((v0.x - mu) * rs, g0.x, b0.x);
    o0.y = fmaf((v0.y - mu) * rs, g0.y, b0.y);
    o0.z = fmaf((v0.z - mu) * rs, g0.z, b0.z);
    o0.w = fmaf((v0.w - mu) * rs, g0.w, b0.w);
    o1.x = fmaf((v1.x - mu) * rs, g1.x, b1.x);
    o1.y = fmaf((v1.y - mu) * rs, g1.y, b1.y);
    o1.z = fmaf((v1.z - mu) * rs, g1.z, b1.z);
    o1.w = fmaf((v1.w - mu) * rs, g1.w, b1.w);
    *(short8*)(q + (size_t)c * TTn + t) = cvt8(o0, o1);
}

// ---------------- bf16 MFMA GEMM ----------------
// EPI 0: +bias[n], f32 store transposed; fused LN partial sums -> psout slot.
// EPI 1: +bias[m], hardswish, bf16 store transposed.
// EPI 2: +bias[m], f32 store normal.
template<bool AF32, int EPI>
__global__ __launch_bounds__(256)
void gemm_mfma(const void* __restrict__ Av, long astride, int lda,
               const unsigned short* __restrict__ Bsrc, long bstride, int ldb,
               const float* __restrict__ bias,
               void* __restrict__ Cv, long cstride, int ldc,
               int K, float* __restrict__ psout) {
    const int tid = threadIdx.x;
    const int lane = tid & 63;
    const int wid = tid >> 6;
    const int wr = wid >> 1, wc = wid & 1;
    const int bz = blockIdx.z;
    const int m0 = blockIdx.y * 64, n0 = blockIdx.x * 128;

    __shared__ unsigned short As[64 * 64];
    __shared__ unsigned short Bs[128 * 64];
    char* AsB = (char*)As;
    char* BsB = (char*)Bs;

    const int ar = tid >> 2, akq = tid & 3;
    const int bn_ = tid >> 1, bkh = (tid & 1) * 32;

    const float* Afp = (const float*)Av + (size_t)bz * astride + (size_t)(m0 + ar) * lda + akq * 16;
    const unsigned short* Ahp = (const unsigned short*)Av + (size_t)bz * astride + (size_t)(m0 + ar) * lda + akq * 16;
    const unsigned short* Bp = Bsrc + (size_t)bz * bstride + (size_t)(n0 + bn_) * ldb + bkh;

    const int awb = ar * 128 + akq * 32;
    const int aswz = (ar & 7) << 4;
    const int bwb = bn_ * 128 + bkh * 2;
    const int bswz = (bn_ & 7) << 4;

    short8 ra0, ra1, rb0, rb1, rb2, rb3;

    auto loadA = [&](int k0) {
        if constexpr (AF32) {
            const float* p = Afp + k0;
            float4 v0 = *(const float4*)(p);
            float4 v1 = *(const float4*)(p + 4);
            float4 v2 = *(const float4*)(p + 8);
            float4 v3 = *(const float4*)(p + 12);
            ra0 = cvt8(v0, v1);
            ra1 = cvt8(v2, v3);
        } else {
            ra0 = *(const short8*)(Ahp + k0);
            ra1 = *(const short8*)(Ahp + k0 + 8);
        }
    };
    auto loadB = [&](int k0) {
        rb0 = *(const short8*)(Bp + k0);
        rb1 = *(const short8*)(Bp + k0 + 8);
        rb2 = *(const short8*)(Bp + k0 + 16);
        rb3 = *(const short8*)(Bp + k0 + 24);
    };
    auto stage = [&]() {
        *(short8*)(AsB + ((awb) ^ aswz)) = ra0;
        *(short8*)(AsB + ((awb + 16) ^ aswz)) = ra1;
        *(short8*)(BsB + ((bwb) ^ bswz)) = rb0;
        *(short8*)(BsB + ((bwb + 16) ^ bswz)) = rb1;
        *(short8*)(BsB + ((bwb + 32) ^ bswz)) = rb2;
        *(short8*)(BsB + ((bwb + 48) ^ bswz)) = rb3;
    };

    const int fl = lane & 15;
    const int fkb = (lane >> 4) * 16;
    const int amb = (wr * 32 + fl) * 128;
    const int bnb = (wc * 64 + fl) * 128;
    const int fswz = (fl & 7) << 4;

    f32x4 acc[2][4];
#pragma unroll
    for (int i = 0; i < 2; ++i)
#pragma unroll
        for (int j = 0; j < 4; ++j) acc[i][j] = (f32x4){0.f, 0.f, 0.f, 0.f};

    const int nkt = (EPI == 0) ? (K >> 6) : ((m0 >> 6) + 1);

    loadA(0);
    loadB(0);
    for (int kt = 0; kt < nkt; ++kt) {
        __syncthreads();
        stage();
        __syncthreads();
        if (kt + 1 < nkt) { loadA((kt + 1) * 64); loadB((kt + 1) * 64); }
#pragma unroll
        for (int ks = 0; ks < 2; ++ks) {
            const int kb = ks * 64 + fkb;
            short8 af0 = *(const short8*)(AsB + ((amb + kb) ^ fswz));
            short8 af1 = *(const short8*)(AsB + ((amb + 2048 + kb) ^ fswz));
            short8 bf0 = *(const short8*)(BsB + ((bnb + kb) ^ fswz));
            short8 bf1 = *(const short8*)(BsB + ((bnb + 2048 + kb) ^ fswz));
            short8 bf2 = *(const short8*)(BsB + ((bnb + 4096 + kb) ^ fswz));
            short8 bf3 = *(const short8*)(BsB + ((bnb + 6144 + kb) ^ fswz));
            acc[0][0] = __builtin_amdgcn_mfma_f32_16x16x32_bf16(af0, bf0, acc[0][0], 0, 0, 0);
            acc[0][1] = __builtin_amdgcn_mfma_f32_16x16x32_bf16(af0, bf1, acc[0][1], 0, 0, 0);
            acc[0][2] = __builtin_amdgcn_mfma_f32_16x16x32_bf16(af0, bf2, acc[0][2], 0, 0, 0);
            acc[0][3] = __builtin_amdgcn_mfma_f32_16x16x32_bf16(af0, bf3, acc[0][3], 0, 0, 0);
            acc[1][0] = __builtin_amdgcn_mfma_f32_16x16x32_bf16(af1, bf0, acc[1][0], 0, 0, 0);
            acc[1][1] = __builtin_amdgcn_mfma_f32_16x16x32_bf16(af1, bf1, acc[1][1], 0, 0, 0);
            acc[1][2] = __builtin_amdgcn_mfma_f32_16x16x32_bf16(af1, bf2, acc[1][2], 0, 0, 0);
            acc[1][3] = __builtin_amdgcn_mfma_f32_16x16x32_bf16(af1, bf3, acc[1][3], 0, 0, 0);
        }
    }

    const int lrow = (lane >> 4) * 4;
    float s_ = 0.f, ss_ = 0.f;   // LN partial sums (EPI 0 only)
#pragma unroll
    for (int mf = 0; mf < 2; ++mf) {
        const int trow = m0 + wr * 32 + mf * 16 + lrow;
#pragma unroll
        for (int nf = 0; nf < 4; ++nf) {
            const int col = n0 + wc * 64 + nf * 16 + fl;
            f32x4 v = acc[mf][nf];
            if (EPI == 0) {
                v += bias[col];
#pragma unroll
                for (int r = 0; r < 4; ++r) { s_ += v[r]; ss_ = fmaf(v[r], v[r], ss_); }
                float* Cb = (float*)Cv + (size_t)bz * cstride + (size_t)col * ldc + trow;
                *(f32x4*)Cb = v;
            } else if (EPI == 1) {
                f32x4 bv = *(const f32x4*)(bias + trow);
                v += bv;
                unsigned short* Cb = (unsigned short*)Cv + (size_t)bz * cstride + (size_t)col * ldc + trow;
                short4v pk;
#pragma unroll
                for (int r = 0; r < 4; ++r) {
                    float t = v[r];
                    float u = fminf(fmaxf(t + 3.f, 0.f), 6.f);
                    t = t * u * (1.f / 6.f);
                    pk[r] = (short)f2b(t);
                }
                *(short4v*)Cb = pk;
            } else {
                f32x4 bv = *(const f32x4*)(bias + trow);
                v += bv;
                float* Cb = (float*)Cv + (size_t)bz * cstride + (size_t)trow * ldc + col;
#pragma unroll
                for (int r = 0; r < 4; ++r) Cb[(size_t)r * ldc] = v[r];
            }
        }
    }

    if (EPI == 0) {
        // block-reduce s_/ss_ -> one slot per block (deterministic, no atomics)
#pragma unroll
        for (int o = 32; o > 0; o >>= 1) { s_ += __shfl_down(s_, o); ss_ += __shfl_down(ss_, o); }
        __shared__ float rsm[8];
        if (lane == 0) { rsm[wid] = s_; rsm[wid + 4] = ss_; }
        __syncthreads();
        if (tid == 0) {
            float S = rsm[0] + rsm[1] + rsm[2] + rsm[3];
            float SS = rsm[4] + rsm[5] + rsm[6] + rsm[7];
            int nslots = gridDim.x * gridDim.y;
            int slot = blockIdx.y * gridDim.x + blockIdx.x;
            psout[((size_t)bz * nslots + slot) * 2 + 0] = S;
            psout[((size_t)bz * nslots + slot) * 2 + 1] = SS;
        }
    }
}

// ---------------- launch ----------------
extern "C" void kernel_launch(void* const* d_in, const int* in_sizes, int n_in,
                              void* d_out, int out_size, void* d_ws, size_t ws_size,
                              hipStream_t stream) {
    const float* x    = (const float*)d_in[0];
    const float* cw1  = (const float*)d_in[1];
    const float* cb1  = (const float*)d_in[2];
    const float* cw2  = (const float*)d_in[3];
    const float* cb2  = (const float*)d_in[4];
    const float* ln1g = (const float*)d_in[5];
    const float* ln1b = (const float*)d_in[6];
    const float* ln2g = (const float*)d_in[7];
    const float* ln2b = (const float*)d_in[8];
    const float* tw1  = (const float*)d_in[9];
    const float* tb1  = (const float*)d_in[10];
    const float* tw2  = (const float*)d_in[11];
    const float* tb2  = (const float*)d_in[12];
    float* out = (float*)d_out;

    char* w = (char*)d_ws;
    unsigned short* catb = (unsigned short*)w;                  // bf16 [B][C][TT]
    unsigned short* z1b  = (unsigned short*)(w + 29360128);     // bf16 [B][C][TT]
    float*          c1t  = (float*)(w + 58720256);              // f32 [B][C][T1]
    float*          c2t  = (float*)(w + 75497472);              // f32 [B][C][T2]
    unsigned short* w1rT = (unsigned short*)(w + 83886080);
    unsigned short* w2rT = (unsigned short*)(w + 84148224);
    unsigned short* wm1b = (unsigned short*)(w + 84672512);
    unsigned short* wm2b = (unsigned short*)(w + 85073920);
    float*          gt1  = (float*)(w + 85475328);
    float*          bt1  = (float*)(w + 85606400);
    float*          gt2  = (float*)(w + 85737472);
    float*          bt2  = (float*)(w + 85803008);
    float*          ps1  = (float*)(w + 85868544);              // [B][4][2]
    float*          ps2  = (float*)(w + 85876736);              // [B][2][2]

    // 1) all prep in one launch (892,928 flat elems)
    prep_all<<<3488, 256, 0, stream>>>(cw1, cw2, tw1, tw2, ln1g, ln1b, ln2g, ln2b,
                                       w1rT, w2rT, wm1b, wm2b, gt1, bt1, gt2, bt2);

    // 2) x -> catb (channel-major, t in [0,256))
    xpose_kernel<<<dim3(4, 4, Bn), 256, 0, stream>>>(x, catb);

    // 3) conv1 -> c1t (+ LN1 partial sums)
    gemm_mfma<true, 0><<<dim3(2, 2, Bn), 256, 0, stream>>>(
        x, 65536L, 512, w1rT, 0L, 512, cb1, c1t, (long)Cn * T1n, T1n, 512, ps1);
    // 4) conv2 -> c2t (+ LN2 partial sums)
    gemm_mfma<true, 0><<<dim3(2, 1, Bn), 256, 0, stream>>>(
        x, 65536L, 1024, w2rT, 0L, 1024, cb2, c2t, (long)Cn * T2n, T2n, 1024, ps2);

    // 5) both layernorm applies
    ln_apply_both<<<dim3(24, Bn), 256, 0, stream>>>(c1t, c2t, gt1, bt1, gt2, bt2, ps1, ps2, catb);

    // 6) TriU layer 1 -> z1b (bf16, hardswish)
    gemm_mfma<false, 1><<<dim3(2, 7, Bn), 256, 0, stream>>>(
        wm1b, 0L, TTn, catb, (long)TTn * Cn, TTn, tb1, z1b, (long)TTn * Cn, TTn, TTn, nullptr);

    // 7) TriU layer 2 -> out (f32 [b][t][c])
    gemm_mfma<false, 2><<<dim3(2, 7, Bn), 256, 0, stream>>>(
        wm2b, 0L, TTn, z1b, (long)TTn * Cn, TTn, tb2, out, (long)TTn * Cn, Cn, TTn, nullptr);
}